// Round 1
// baseline (144.295 us; speedup 1.0000x reference)
//
#include <hip/hip_runtime.h>
#include <math.h>

// Problem constants: B=4, N=8192, Din=Dout=128, fp32 in/out.
#define NNODES 8192
#define D 128
#define NBATCH 4

// ---------------------------------------------------------------------------
// Kernel G: gate[row][o] = sigmoid( sum_k x[row][k]*W[k][o] + bias[o] )
// rows = B*N = 32768. 512 blocks x 128 threads; 64 rows per block.
// LDS: xs 64x132 fp32 (33.8KB) + W chunk 32x132 (16.9KB) = ~51KB -> 2 blocks/CU.
// Per-thread tile: 8 rows x 8 o (o split in two 4-float segments 64 apart to
// keep ds_read_b128 bank conflicts <=2-way; rows split 4+4 with +32 offset).
// ---------------------------------------------------------------------------
__global__ __launch_bounds__(128) void gate_kernel(
    const float* __restrict__ x, const float* __restrict__ W,
    const float* __restrict__ bias, float* __restrict__ gate)
{
    __shared__ float xs[64 * 132];
    __shared__ float Wc[32 * 132];
    const int t   = threadIdx.x;
    const int blk = blockIdx.x;

    // stage 64 rows of x (row stride 132 in LDS)
    const float4* xsrc = (const float4*)(x + (size_t)blk * 64 * D);
    for (int idx = t; idx < 64 * 32; idx += 128) {
        int r = idx >> 5, c = idx & 31;
        *(float4*)&xs[r * 132 + c * 4] = xsrc[idx];
    }

    const int rh = t >> 4;   // 0..7  -> rows {rh*4+j} U {32+rh*4+j}
    const int oc = t & 15;   // o segments {oc*4..+3} U {64+oc*4..+3}

    float acc[8][8];
    float4 b0 = *(const float4*)&bias[oc * 4];
    float4 b1 = *(const float4*)&bias[64 + oc * 4];
#pragma unroll
    for (int j = 0; j < 8; ++j) {
        acc[j][0] = b0.x; acc[j][1] = b0.y; acc[j][2] = b0.z; acc[j][3] = b0.w;
        acc[j][4] = b1.x; acc[j][5] = b1.y; acc[j][6] = b1.z; acc[j][7] = b1.w;
    }

    for (int kc = 0; kc < 4; ++kc) {
        __syncthreads();
        const float4* Wsrc = (const float4*)(W + kc * 32 * D);
        for (int idx = t; idx < 32 * 32; idx += 128) {
            int r = idx >> 5, c = idx & 31;
            *(float4*)&Wc[r * 132 + c * 4] = Wsrc[idx];
        }
        __syncthreads();

        for (int k4 = 0; k4 < 32; k4 += 4) {
            float4 xv[8];
#pragma unroll
            for (int j = 0; j < 8; ++j) {
                int rp = (j < 4) ? (rh * 4 + j) : (32 + rh * 4 + (j - 4));
                xv[j] = *(const float4*)&xs[rp * 132 + kc * 32 + k4];
            }
#pragma unroll
            for (int q = 0; q < 4; ++q) {
                float4 w0 = *(const float4*)&Wc[(k4 + q) * 132 + oc * 4];
                float4 w1 = *(const float4*)&Wc[(k4 + q) * 132 + 64 + oc * 4];
                float wv[8] = {w0.x, w0.y, w0.z, w0.w, w1.x, w1.y, w1.z, w1.w};
#pragma unroll
                for (int j = 0; j < 8; ++j) {
                    float xq = ((const float*)&xv[j])[q];
#pragma unroll
                    for (int o = 0; o < 8; ++o) acc[j][o] += xq * wv[o];
                }
            }
        }
    }

    // sigmoid + store
#pragma unroll
    for (int j = 0; j < 8; ++j) {
        int rp = (j < 4) ? (rh * 4 + j) : (32 + rh * 4 + (j - 4));
        size_t row = (size_t)blk * 64 + rp;
        float4 g0, g1;
        g0.x = 1.0f / (1.0f + __expf(-acc[j][0]));
        g0.y = 1.0f / (1.0f + __expf(-acc[j][1]));
        g0.z = 1.0f / (1.0f + __expf(-acc[j][2]));
        g0.w = 1.0f / (1.0f + __expf(-acc[j][3]));
        g1.x = 1.0f / (1.0f + __expf(-acc[j][4]));
        g1.y = 1.0f / (1.0f + __expf(-acc[j][5]));
        g1.z = 1.0f / (1.0f + __expf(-acc[j][6]));
        g1.w = 1.0f / (1.0f + __expf(-acc[j][7]));
        *(float4*)&gate[row * D + oc * 4]      = g0;
        *(float4*)&gate[row * D + 64 + oc * 4] = g1;
    }
}

// ---------------------------------------------------------------------------
// Kernel P: per-block max-pool over a 128-node slice.
// grid 256 = B * 64 slices; block 256 threads, per-thread 8i x 8o accumulator.
// slab[pb][i][o] = max over block's nodes of x[n][i]*gate[n][o].
// Nodes processed in pairs -> fmaxf(acc, fmaxf(p0,p1)) fuses to v_max3_f32.
// ---------------------------------------------------------------------------
__global__ __launch_bounds__(256) void pool_kernel(
    const float* __restrict__ x, const float* __restrict__ gate,
    float* __restrict__ slab)
{
    __shared__ float xs[32 * D];
    __shared__ float gs[32 * D];
    const int t  = threadIdx.x;
    const int pb = blockIdx.x;          // 0..255
    const int b  = pb >> 6;
    const int nb = pb & 63;             // node slice: nb*128 .. +128
    const size_t base = ((size_t)b * NNODES + (size_t)nb * 128) * D;

    const int ti = t >> 4;  // i segments {ti*4..+3} U {64+ti*4..+3}
    const int to = t & 15;  // o segments {to*4..+3} U {64+to*4..+3}

    float acc[8][8];
#pragma unroll
    for (int ii = 0; ii < 8; ++ii)
#pragma unroll
        for (int oo = 0; oo < 8; ++oo) acc[ii][oo] = -INFINITY;

    for (int ch = 0; ch < 4; ++ch) {
        __syncthreads();
        const float4* xsrc = (const float4*)(x + base + (size_t)ch * 32 * D);
        const float4* gsrc = (const float4*)(gate + base + (size_t)ch * 32 * D);
        for (int idx = t; idx < 1024; idx += 256) {
            ((float4*)xs)[idx] = xsrc[idx];
            ((float4*)gs)[idx] = gsrc[idx];
        }
        __syncthreads();

        for (int c = 0; c < 32; c += 2) {
            float4 xa0 = *(const float4*)&xs[c * D + ti * 4];
            float4 xa1 = *(const float4*)&xs[c * D + 64 + ti * 4];
            float4 xb0 = *(const float4*)&xs[(c + 1) * D + ti * 4];
            float4 xb1 = *(const float4*)&xs[(c + 1) * D + 64 + ti * 4];
            float4 ga0 = *(const float4*)&gs[c * D + to * 4];
            float4 ga1 = *(const float4*)&gs[c * D + 64 + to * 4];
            float4 gb0 = *(const float4*)&gs[(c + 1) * D + to * 4];
            float4 gb1 = *(const float4*)&gs[(c + 1) * D + 64 + to * 4];
            float xA[8] = {xa0.x, xa0.y, xa0.z, xa0.w, xa1.x, xa1.y, xa1.z, xa1.w};
            float xB[8] = {xb0.x, xb0.y, xb0.z, xb0.w, xb1.x, xb1.y, xb1.z, xb1.w};
            float gA[8] = {ga0.x, ga0.y, ga0.z, ga0.w, ga1.x, ga1.y, ga1.z, ga1.w};
            float gB[8] = {gb0.x, gb0.y, gb0.z, gb0.w, gb1.x, gb1.y, gb1.z, gb1.w};
#pragma unroll
            for (int ii = 0; ii < 8; ++ii) {
#pragma unroll
                for (int oo = 0; oo < 8; ++oo) {
                    float p0 = xA[ii] * gA[oo];
                    float p1 = xB[ii] * gB[oo];
                    acc[ii][oo] = fmaxf(acc[ii][oo], fmaxf(p0, p1));  // v_max3
                }
            }
        }
    }

    // write private slab (no atomics)
    float* sdst = slab + (size_t)pb * (D * D);
#pragma unroll
    for (int ii = 0; ii < 8; ++ii) {
        int ip = (ii < 4) ? (ti * 4 + ii) : (64 + ti * 4 + (ii - 4));
        float4 v0 = {acc[ii][0], acc[ii][1], acc[ii][2], acc[ii][3]};
        float4 v1 = {acc[ii][4], acc[ii][5], acc[ii][6], acc[ii][7]};
        *(float4*)&sdst[ip * D + to * 4]      = v0;
        *(float4*)&sdst[ip * D + 64 + to * 4] = v1;
    }
}

// ---------------------------------------------------------------------------
// Kernel R: out[b][o] = (1/128) * sum_i  max over 64 slabs of slab[b*64+s][i][o]
// grid 256 = B * 64 i-pairs; block 256 threads (2 i-rows x 128 o).
// ---------------------------------------------------------------------------
__global__ __launch_bounds__(256) void reduce_kernel(
    const float* __restrict__ slab, float* __restrict__ out)
{
    __shared__ float red[128];
    const int t  = threadIdx.x;
    const int rb = blockIdx.x;          // 0..255
    const int b  = rb >> 6;
    const int ig = rb & 63;
    const int o  = t & 127;
    const int ih = t >> 7;
    const int i  = ig * 2 + ih;

    const float* p = slab + (size_t)(b * 64) * (D * D) + (size_t)i * D + o;
    float m = -INFINITY;
#pragma unroll 8
    for (int s = 0; s < 64; ++s) m = fmaxf(m, p[(size_t)s * (D * D)]);

    if (ih == 1) red[o] = m;
    __syncthreads();
    if (ih == 0) atomicAdd(&out[b * D + o], (m + red[o]) * 0.0078125f);
}

// ---------------------------------------------------------------------------
extern "C" void kernel_launch(void* const* d_in, const int* in_sizes, int n_in,
                              void* d_out, int out_size, void* d_ws, size_t ws_size,
                              hipStream_t stream)
{
    const float* x    = (const float*)d_in[0];   // (4, 8192, 128)
    const float* W    = (const float*)d_in[1];   // (128, 128)
    const float* bias = (const float*)d_in[2];   // (128,)
    float* out  = (float*)d_out;                 // (4, 128)

    float* gate = (float*)d_ws;                          // 32768*128 fp32 = 16 MB
    float* slab = gate + (size_t)NBATCH * NNODES * D;    // 256*128*128 fp32 = 16 MB

    hipMemsetAsync(d_out, 0, (size_t)out_size * sizeof(float), stream);
    gate_kernel<<<512, 128, 0, stream>>>(x, W, bias, gate);
    pool_kernel<<<256, 256, 0, stream>>>(x, gate, slab);
    reduce_kernel<<<256, 256, 0, stream>>>(slab, out);
}

// Round 2
// 133.172 us; speedup vs baseline: 1.0835x; 1.0835x over previous
//
#include <hip/hip_runtime.h>
#include <math.h>

// Problem: B=4, N=8192, Din=Dout=128 fp32.
// out[b][o] = (1/128) * sum_i max_n ( x[b][n][i] * sigmoid(x@W+b)[b][n][o] )
#define NNODES 8192
#define D 128
#define NBATCH 4

// float -> bf16 (round to nearest even), as uint16 in low bits
__device__ inline unsigned int f2bf(float f) {
    unsigned int u = __float_as_uint(f);
    return (u + 0x7FFFu + ((u >> 16) & 1u)) >> 16;
}

// ---------------------------------------------------------------------------
// Fused gate+pool. grid 1024 = B*256 node-slices of 32 nodes; 256 threads.
// Phase 1 (GEMM): gate[32][128] = sigmoid(xs @ W + bias) into LDS.
//   thread tile 4 rows x 4 o (rg=t>>5 rows rg*4..+3, oc=t&31 o oc*4..+3).
//   W staged in 16-k chunks (8 KB). All LDS reads <=2-way conflicts:
//   x reads broadcast across 32 lanes, 2 distinct rows/wave (2-way alias,
//   free per m136); W reads are consecutive-lane b128.
// Phase 2 (pool): acc[8i][8o] = max over 32 nodes of x[n][i]*gate[n][o],
//   node-paired so fmaxf(acc,fmaxf(p0,p1)) fuses to v_max3_f32.
// Slab written as bf16 (halves reduce traffic; err <= 2^-9*|slab| ~ 0.01).
// LDS 16+16+8 = 40 KB -> exactly 4 blocks/CU = 16 waves/CU.
// ---------------------------------------------------------------------------
__global__ __launch_bounds__(256, 4) void fused_gate_pool(
    const float* __restrict__ x, const float* __restrict__ W,
    const float* __restrict__ bias, unsigned short* __restrict__ slab)
{
    __shared__ float xs[32 * 128];   // 16 KB
    __shared__ float gs[32 * 128];   // 16 KB
    __shared__ float Wc[16 * 128];   // 8 KB
    const int t   = threadIdx.x;
    const int blk = blockIdx.x;                       // = b*256 + slice
    const size_t base = (size_t)blk * 32 * D;         // slices contiguous in x

    // stage 32 rows of x (4 float4 per thread, coalesced)
    const float4* xsrc = (const float4*)(x + base);
    for (int idx = t; idx < 1024; idx += 256)
        ((float4*)xs)[idx] = xsrc[idx];

    // ---- phase 1: GEMM + sigmoid ----
    const int rg = t >> 5;   // 0..7 -> rows rg*4..rg*4+3
    const int oc = t & 31;   // o = oc*4..oc*4+3

    float4 bb = *(const float4*)&bias[oc * 4];
    float acc[4][4];
#pragma unroll
    for (int j = 0; j < 4; ++j) {
        acc[j][0] = bb.x; acc[j][1] = bb.y; acc[j][2] = bb.z; acc[j][3] = bb.w;
    }

    for (int kc = 0; kc < 8; ++kc) {
        __syncthreads();   // Wc free to overwrite (and xs staged, 1st iter)
        const float4* Wsrc = (const float4*)(W + kc * 16 * D);
        for (int idx = t; idx < 512; idx += 256)
            ((float4*)Wc)[idx] = Wsrc[idx];
        __syncthreads();

#pragma unroll
        for (int kg = 0; kg < 4; ++kg) {
            const int k0 = kg * 4;
            float4 xv[4];
#pragma unroll
            for (int j = 0; j < 4; ++j)
                xv[j] = *(const float4*)&xs[(rg * 4 + j) * D + kc * 16 + k0];
#pragma unroll
            for (int q = 0; q < 4; ++q) {
                float4 wv = *(const float4*)&Wc[(k0 + q) * D + oc * 4];
#pragma unroll
                for (int j = 0; j < 4; ++j) {
                    float xq = ((const float*)&xv[j])[q];
                    acc[j][0] += xq * wv.x;
                    acc[j][1] += xq * wv.y;
                    acc[j][2] += xq * wv.z;
                    acc[j][3] += xq * wv.w;
                }
            }
        }
    }

    // sigmoid -> gs
#pragma unroll
    for (int j = 0; j < 4; ++j) {
        float4 g;
        g.x = 1.0f / (1.0f + __expf(-acc[j][0]));
        g.y = 1.0f / (1.0f + __expf(-acc[j][1]));
        g.z = 1.0f / (1.0f + __expf(-acc[j][2]));
        g.w = 1.0f / (1.0f + __expf(-acc[j][3]));
        *(float4*)&gs[(rg * 4 + j) * D + oc * 4] = g;
    }
    __syncthreads();

    // ---- phase 2: max-pool over the 32 nodes ----
    const int ti = t >> 4;   // i segments {ti*4..+3} U {64+ti*4..+3}
    const int to = t & 15;   // o segments {to*4..+3} U {64+to*4..+3}

    float pacc[8][8];
#pragma unroll
    for (int ii = 0; ii < 8; ++ii)
#pragma unroll
        for (int oo = 0; oo < 8; ++oo) pacc[ii][oo] = -INFINITY;

    for (int c = 0; c < 32; c += 2) {
        float4 xa0 = *(const float4*)&xs[c * D + ti * 4];
        float4 xa1 = *(const float4*)&xs[c * D + 64 + ti * 4];
        float4 xb0 = *(const float4*)&xs[(c + 1) * D + ti * 4];
        float4 xb1 = *(const float4*)&xs[(c + 1) * D + 64 + ti * 4];
        float4 ga0 = *(const float4*)&gs[c * D + to * 4];
        float4 ga1 = *(const float4*)&gs[c * D + 64 + to * 4];
        float4 gb0 = *(const float4*)&gs[(c + 1) * D + to * 4];
        float4 gb1 = *(const float4*)&gs[(c + 1) * D + 64 + to * 4];
        float xA[8] = {xa0.x, xa0.y, xa0.z, xa0.w, xa1.x, xa1.y, xa1.z, xa1.w};
        float xB[8] = {xb0.x, xb0.y, xb0.z, xb0.w, xb1.x, xb1.y, xb1.z, xb1.w};
        float gA[8] = {ga0.x, ga0.y, ga0.z, ga0.w, ga1.x, ga1.y, ga1.z, ga1.w};
        float gB[8] = {gb0.x, gb0.y, gb0.z, gb0.w, gb1.x, gb1.y, gb1.z, gb1.w};
#pragma unroll
        for (int ii = 0; ii < 8; ++ii) {
#pragma unroll
            for (int oo = 0; oo < 8; ++oo) {
                float p0 = xA[ii] * gA[oo];
                float p1 = xB[ii] * gB[oo];
                pacc[ii][oo] = fmaxf(pacc[ii][oo], fmaxf(p0, p1));  // v_max3
            }
        }
    }

    // write private slab as bf16 (no atomics); rows 256B, uint2 stores
    unsigned short* sd = slab + (size_t)blk * (D * D);
#pragma unroll
    for (int ii = 0; ii < 8; ++ii) {
        int ip = (ii < 4) ? (ti * 4 + ii) : (64 + ti * 4 + (ii - 4));
        unsigned int h0 = f2bf(pacc[ii][0]) | (f2bf(pacc[ii][1]) << 16);
        unsigned int h1 = f2bf(pacc[ii][2]) | (f2bf(pacc[ii][3]) << 16);
        unsigned int h2 = f2bf(pacc[ii][4]) | (f2bf(pacc[ii][5]) << 16);
        unsigned int h3 = f2bf(pacc[ii][6]) | (f2bf(pacc[ii][7]) << 16);
        uint2 v0 = {h0, h1};
        uint2 v1 = {h2, h3};
        *(uint2*)&sd[ip * D + to * 4]      = v0;
        *(uint2*)&sd[ip * D + 64 + to * 4] = v1;
    }
}

// ---------------------------------------------------------------------------
// Reduce: out[b][o] = (1/128) * sum_i max over 256 slabs of slab[b*256+s][i][o]
// grid 512 = B * 128 i-rows; 256 threads = 2-way s-split x 128 o.
// ---------------------------------------------------------------------------
__global__ __launch_bounds__(256) void reduce_kernel(
    const unsigned short* __restrict__ slab, float* __restrict__ out)
{
    __shared__ float red[128];
    const int t  = threadIdx.x;
    const int rb = blockIdx.x;      // 0..511
    const int b  = rb >> 7;
    const int i  = rb & 127;
    const int o  = t & 127;
    const int sh = t >> 7;          // 0 or 1

    const unsigned short* p =
        slab + ((size_t)(b * 256 + sh)) * (D * D) + (size_t)i * D + o;
    float m = -INFINITY;
#pragma unroll 8
    for (int s = 0; s < 128; ++s) {
        unsigned int v = p[(size_t)s * 2 * (D * D)];
        m = fmaxf(m, __uint_as_float(v << 16));
    }

    if (sh == 1) red[o] = m;
    __syncthreads();
    if (sh == 0)
        atomicAdd(&out[b * D + o], fmaxf(m, red[o]) * 0.0078125f);
}

// ---------------------------------------------------------------------------
extern "C" void kernel_launch(void* const* d_in, const int* in_sizes, int n_in,
                              void* d_out, int out_size, void* d_ws, size_t ws_size,
                              hipStream_t stream)
{
    const float* x    = (const float*)d_in[0];   // (4, 8192, 128)
    const float* W    = (const float*)d_in[1];   // (128, 128)
    const float* bias = (const float*)d_in[2];   // (128,)
    float* out = (float*)d_out;                  // (4, 128)

    unsigned short* slab = (unsigned short*)d_ws;  // 1024 * 16384 bf16 = 32 MB

    hipMemsetAsync(d_out, 0, (size_t)out_size * sizeof(float), stream);
    fused_gate_pool<<<1024, 256, 0, stream>>>(x, W, bias, slab);
    reduce_kernel<<<512, 256, 0, stream>>>(slab, out);
}

// Round 5
// 113.666 us; speedup vs baseline: 1.2695x; 1.1716x over previous
//
#include <hip/hip_runtime.h>
#include <math.h>

// Problem: B=4, N=8192, Din=Dout=128 fp32.
// out[b][o] = (1/128) * sum_i max_n ( x[b][n][i] * sigmoid(x@W+b)[b][n][o] )
#define D 128
#define NNODES 8192
#define NBATCH 4

typedef _Float16 f16x8 __attribute__((ext_vector_type(8)));
typedef _Float16 f16x4 __attribute__((ext_vector_type(4)));
typedef _Float16 f16x2 __attribute__((ext_vector_type(2)));
typedef float f32x4 __attribute__((ext_vector_type(4)));

union U32F2 { unsigned int u; f16x2 f; };
union U4F8  { uint4 u; f16x8 f; };
union HU    { _Float16 h; unsigned short s; };

__device__ inline f16x2 u2f(unsigned int v) { U32F2 c; c.u = v; return c.f; }
__device__ inline unsigned int f2u(f16x2 v) { U32F2 c; c.f = v; return c.u; }
__device__ inline f16x2 pkmax(f16x2 a, f16x2 b) {
    return __builtin_elementwise_max(a, b);   // v_pk_max_f16
}
// max of the two halves of a packed f16x2, result in low half (high = junk)
__device__ inline unsigned int fold2(unsigned int a) {
    return f2u(pkmax(u2f(a), u2f(a >> 16))) & 0xFFFFu;
}

// ---------------------------------------------------------------------------
// Precompute MFMA B-fragments of W^T as fp16, laid out per-lane so each wave
// fetches one fragment with a single coalesced dwordx4:
//   wfrag[(otile*4 + kstep)*64 + lane] = 8 halves of W[k][o],
//     o = otile*16 + (lane&15), k = kstep*32 + (lane>>4)*8 + j  (j=0..7)
// B-operand layout for mfma_f32_16x16x32: n = lane&15, k = quad*8 + j.
// (Any k-grouping error cancels: A and B index k identically per lane.)
// 2048 entries * 16 B = 32 KB, L2-resident for the whole fused kernel.
// ---------------------------------------------------------------------------
__global__ __launch_bounds__(256) void wfrag_kernel(
    const float* __restrict__ W, uint4* __restrict__ wfrag)
{
    int e    = blockIdx.x * 256 + threadIdx.x;   // 0..2047
    int lane = e & 63, ks = (e >> 6) & 3, ot = e >> 8;
    int o  = ot * 16 + (lane & 15);
    int kb = ks * 32 + (lane >> 4) * 8;
    f16x8 f;
#pragma unroll
    for (int j = 0; j < 8; ++j) f[j] = (_Float16)W[(kb + j) * D + o];
    U4F8 c; c.f = f;
    wfrag[e] = c.u;
}

// ---------------------------------------------------------------------------
// Fused gate+pool. grid 1024 = B*256 slices of 32 nodes; 256 threads.
// LDS 24.5 KB; VGPR capped 128 via launch_bounds(256,4) -> 4 blocks/CU,
// all 1024 blocks resident in one round. Only 2 barriers per block.
//
// Phase 1 (MFMA GEMM): gate[32][128] = sigmoid(x@W + bias).
//   Wave w: row-stripe = w&1 (16 nodes), o-half = w>>1 (4 o-tiles);
//   A-frag: x fp16 from LDS xA[32][136] (pad -> rows 16B-aligned, 2-way banks);
//   B-frags: global dwordx4 from wfrag (L2-resident). 16 MFMA/wave.
//   C/D layout: col=lane&15, row=(lane>>4)*4+reg (m89-verified).
// Phase 2 (pool, packed fp16): node-pairs packed in f16x2;
//   acc[8i][8o] via v_pk_mul_f16 + v_pk_max_f16 (1 inst / product).
// Slab: fp16 [i][o] = 128*128*2B = 32 KB = 4096 uint2 per block.  << R4 bug
//   was a 2048-uint2 stride here (blocks overlapped); now 4096. >>
// ---------------------------------------------------------------------------
__global__ __launch_bounds__(256, 4) void fused_gate_pool(
    const float* __restrict__ x, const float* __restrict__ bias,
    const uint4* __restrict__ wfrag, uint2* __restrict__ slab)
{
    __shared__ _Float16     xA[32 * 136];   // 8.5 KB, GEMM A layout
    __shared__ unsigned int xh2[16 * 128];  // 8 KB, pool layout (node-pair f16x2)
    __shared__ unsigned int gh2[16 * 128];  // 8 KB, gate  (node-pair f16x2)

    const int t    = threadIdx.x;
    const int blk  = blockIdx.x;            // b*256 + slice
    const size_t base = (size_t)blk * 32 * D;
    const int lane = t & 63, wave = t >> 6;
    const int stripe = wave & 1, oh = wave >> 1;
    const int quad = lane >> 4, col = lane & 15;

    // ---- stage x: fp16 GEMM copy + f16x2 node-paired pool copy ----
    const float4* xs4 = (const float4*)(x + base);
#pragma unroll
    for (int it = 0; it < 4; ++it) {
        int idx = t + 256 * it;             // 0..1023
        int r = idx >> 5, c4 = idx & 31;
        float4 v = xs4[idx];
        f16x4 h = { (_Float16)v.x, (_Float16)v.y, (_Float16)v.z, (_Float16)v.w };
        *(f16x4*)&xA[r * 136 + c4 * 4] = h;
    }
#pragma unroll
    for (int it = 0; it < 2; ++it) {
        int idx = t + 256 * it;             // 0..511
        int p = idx >> 5, c4 = idx & 31;
        float4 a = xs4[(2 * p) * 32 + c4];      // even node
        float4 b = xs4[(2 * p + 1) * 32 + c4];  // odd node
        uint4 u;
        u.x = f2u((f16x2){(_Float16)a.x, (_Float16)b.x});
        u.y = f2u((f16x2){(_Float16)a.y, (_Float16)b.y});
        u.z = f2u((f16x2){(_Float16)a.z, (_Float16)b.z});
        u.w = f2u((f16x2){(_Float16)a.w, (_Float16)b.w});
        *(uint4*)&xh2[p * 128 + c4 * 4] = u;
    }
    __syncthreads();

    // ---- phase 1: MFMA GEMM + sigmoid -> gh2 ----
    f16x8 af[4];
#pragma unroll
    for (int ks = 0; ks < 4; ++ks)
        af[ks] = *(const f16x8*)&xA[(stripe * 16 + col) * 136 + ks * 32 + quad * 8];

    f32x4 acc[4];
#pragma unroll
    for (int ot = 0; ot < 4; ++ot) acc[ot] = (f32x4){0.f, 0.f, 0.f, 0.f};

#pragma unroll
    for (int ot = 0; ot < 4; ++ot) {
#pragma unroll
        for (int ks = 0; ks < 4; ++ks) {
            U4F8 c; c.u = wfrag[((oh * 4 + ot) * 4 + ks) * 64 + lane];
            acc[ot] = __builtin_amdgcn_mfma_f32_16x16x32_f16(af[ks], c.f, acc[ot], 0, 0, 0);
        }
    }

#pragma unroll
    for (int ot = 0; ot < 4; ++ot) {
        int o = oh * 64 + ot * 16 + col;
        float bv = bias[o];
#pragma unroll
        for (int r = 0; r < 4; ++r) {
            int node = stripe * 16 + quad * 4 + r;   // C/D row
            float g = 1.0f / (1.0f + __expf(-(acc[ot][r] + bv)));
            HU hu; hu.h = (_Float16)g;
            ((unsigned short*)gh2)[(node >> 1) * 256 + o * 2 + (node & 1)] = hu.s;
        }
    }
    __syncthreads();

    // ---- phase 2: packed-fp16 max pool over 16 node-pairs ----
    const int ti = t >> 4;   // i segs {ti*4..+3} U {64+ti*4..+3}
    const int to = t & 15;   // o segs {to*4..+3} U {64+to*4..+3}
    const f16x2 NEGINF = u2f(0xFC00FC00u);

    f16x2 pa[8][8];
#pragma unroll
    for (int ii = 0; ii < 8; ++ii)
#pragma unroll
        for (int oo = 0; oo < 8; ++oo) pa[ii][oo] = NEGINF;

    for (int p = 0; p < 16; ++p) {
        uint4 xa = *(const uint4*)&xh2[p * 128 + ti * 4];
        uint4 xb = *(const uint4*)&xh2[p * 128 + 64 + ti * 4];
        uint4 ga = *(const uint4*)&gh2[p * 128 + to * 4];
        uint4 gb = *(const uint4*)&gh2[p * 128 + 64 + to * 4];
        f16x2 xv[8] = {u2f(xa.x), u2f(xa.y), u2f(xa.z), u2f(xa.w),
                       u2f(xb.x), u2f(xb.y), u2f(xb.z), u2f(xb.w)};
        f16x2 gv[8] = {u2f(ga.x), u2f(ga.y), u2f(ga.z), u2f(ga.w),
                       u2f(gb.x), u2f(gb.y), u2f(gb.z), u2f(gb.w)};
#pragma unroll
        for (int ii = 0; ii < 8; ++ii)
#pragma unroll
            for (int oo = 0; oo < 8; ++oo)
                pa[ii][oo] = pkmax(pa[ii][oo], xv[ii] * gv[oo]);  // pk_mul + pk_max
    }

    // fold even/odd-node halves (shift+pkmax, no byte-perm) and store fp16 slab
    uint2* sd = slab + (size_t)blk * 4096;   // 4096 uint2 = 32 KB per slab
#pragma unroll
    for (int ii = 0; ii < 8; ++ii) {
        int ip = (ii < 4) ? (ti * 4 + ii) : (64 + ti * 4 + (ii - 4));
        unsigned int a[8];
#pragma unroll
        for (int oo = 0; oo < 8; ++oo) a[oo] = f2u(pa[ii][oo]);
        unsigned int r01 = fold2(a[0]) | (fold2(a[1]) << 16);
        unsigned int r23 = fold2(a[2]) | (fold2(a[3]) << 16);
        unsigned int r45 = fold2(a[4]) | (fold2(a[5]) << 16);
        unsigned int r67 = fold2(a[6]) | (fold2(a[7]) << 16);
        uint2 v0 = {r01, r23};
        uint2 v1 = {r45, r67};
        sd[ip * 32 + to]      = v0;   // o = to*4..+3
        sd[ip * 32 + 16 + to] = v1;   // o = 64+to*4..+3
    }
}

// ---------------------------------------------------------------------------
// Reduce: out[b][o] = (1/128) * sum_i max over 256 slabs (fp16, pk_max).
// grid 512 = (b, i); 256 thr = 64 o-pairs x 4 s-groups. Per-wave loads are
// 256 B contiguous; slab stride = 8192 uints (32 KB).
// ---------------------------------------------------------------------------
__global__ __launch_bounds__(256) void reduce_kernel(
    const unsigned int* __restrict__ slab, float* __restrict__ out)
{
    __shared__ unsigned int red[3][64];
    const int rb = blockIdx.x;        // 0..511
    const int b  = rb >> 7, i = rb & 127;
    const int t  = threadIdx.x;
    const int og = t & 63, sg = t >> 6;

    const unsigned int* p =
        slab + (size_t)(b * 256 + sg * 64) * 8192 + i * 64 + og;
    f16x2 m = u2f(0xFC00FC00u);
#pragma unroll 8
    for (int it = 0; it < 64; ++it)
        m = pkmax(m, u2f(p[(size_t)it * 8192]));

    if (sg) red[sg - 1][og] = f2u(m);
    __syncthreads();
    if (sg == 0) {
        m = pkmax(m, u2f(red[0][og]));
        m = pkmax(m, u2f(red[1][og]));
        m = pkmax(m, u2f(red[2][og]));
        atomicAdd(&out[b * D + og * 2],     (float)m[0] * 0.0078125f);
        atomicAdd(&out[b * D + og * 2 + 1], (float)m[1] * 0.0078125f);
    }
}

// ---------------------------------------------------------------------------
extern "C" void kernel_launch(void* const* d_in, const int* in_sizes, int n_in,
                              void* d_out, int out_size, void* d_ws, size_t ws_size,
                              hipStream_t stream)
{
    const float* x    = (const float*)d_in[0];   // (4, 8192, 128)
    const float* W    = (const float*)d_in[1];   // (128, 128)
    const float* bias = (const float*)d_in[2];   // (128,)
    float* out = (float*)d_out;                  // (4, 128)

    uint4* wfrag = (uint4*)d_ws;                             // 32 KB
    uint2* slab  = (uint2*)((char*)d_ws + 65536);            // 1024 * 32 KB = 32 MB

    (void)hipMemsetAsync(d_out, 0, (size_t)out_size * sizeof(float), stream);
    wfrag_kernel<<<8, 256, 0, stream>>>(W, wfrag);
    fused_gate_pool<<<1024, 256, 0, stream>>>(x, bias, wfrag, slab);
    reduce_kernel<<<512, 256, 0, stream>>>((const unsigned int*)slab, out);
}

// Round 6
// 104.851 us; speedup vs baseline: 1.3762x; 1.0841x over previous
//
#include <hip/hip_runtime.h>
#include <math.h>

// Problem: B=4, N=8192, Din=Dout=128 fp32.
// out[b][o] = (1/128) * sum_i max_n ( x[b][n][i] * sigmoid(x@W+b)[b][n][o] )
#define D 128
#define NNODES 8192
#define NBATCH 4

typedef _Float16 f16x8 __attribute__((ext_vector_type(8)));
typedef _Float16 f16x4 __attribute__((ext_vector_type(4)));
typedef _Float16 f16x2 __attribute__((ext_vector_type(2)));
typedef float f32x4 __attribute__((ext_vector_type(4)));

__device__ inline f16x2 bc(unsigned int v) { return __builtin_bit_cast(f16x2, v); }
__device__ inline unsigned int cb(f16x2 v) { return __builtin_bit_cast(unsigned int, v); }
__device__ inline f16x2 pkmax(f16x2 a, f16x2 b) {
    return __builtin_elementwise_max(a, b);   // v_pk_max_f16
}
// max of the two halves of a packed f16x2, result in low 16 bits
__device__ inline unsigned int fold2(unsigned int a) {
    return cb(pkmax(bc(a), bc(a >> 16))) & 0xFFFFu;
}

// ---------------------------------------------------------------------------
// Precompute MFMA B-fragments of W^T as fp16; one coalesced dwordx4 per lane:
//   wfrag[(otile*4 + kstep)*64 + lane] = 8 halves of W[k][o],
//     o = otile*16 + (lane&15), k = kstep*32 + (lane>>4)*8 + j (j=0..7)
// 2048 entries * 16 B = 32 KB, L2/L3-resident during the fused kernel.
// ---------------------------------------------------------------------------
__global__ __launch_bounds__(256) void wfrag_kernel(
    const float* __restrict__ W, uint4* __restrict__ wfrag)
{
    int e    = blockIdx.x * 256 + threadIdx.x;   // 0..2047
    int lane = e & 63, ks = (e >> 6) & 3, ot = e >> 8;
    int o  = ot * 16 + (lane & 15);
    int kb = ks * 32 + (lane >> 4) * 8;
    f16x8 f;
#pragma unroll
    for (int j = 0; j < 8; ++j) f[j] = (_Float16)W[(kb + j) * D + o];
    wfrag[e] = __builtin_bit_cast(uint4, f);
}

// ---------------------------------------------------------------------------
// Fused gate+pool. grid 1024 = B*256 slices of 32 nodes; 256 threads.
// LDS 24.5 KB, VGPR<=128 via launch_bounds(256,4) -> 4 blocks/CU, one round.
//
// Phase 1 (MFMA): gate = sigmoid(x@W+b). Wave w: stripe=w&1 (16 nodes),
//   o-half=w>>1. A-frags from LDS xA[32][136]; B-frags: 4 hoisted global
//   dwordx4 per o-tile. C/D: col=lane&15, row=(lane>>4)*4+reg (m89).
//   Epilogue packs node-pairs (rows 2r,2r+1 live in the same lane) into one
//   f16x2 -> 8x ds_write_b32 (was 16x scattered b16).
// Phase 2 (pool): FULLY UNROLLED 16 node-pair iters; all ds_read_b128
//   offsets are immediates; 64 updates/iter via v_pk_mul_f16 + v_pk_max_f16.
// Slab: fp16 [i][o] = 32 KB = 4096 uint2 per block.
// ---------------------------------------------------------------------------
__global__ __launch_bounds__(256, 4) void fused_gate_pool(
    const float* __restrict__ x, const float* __restrict__ bias,
    const uint4* __restrict__ wfrag, uint2* __restrict__ slab)
{
    __shared__ _Float16     xA[32 * 136];   // 8.5 KB, GEMM A layout
    __shared__ unsigned int xh2[16 * 128];  // 8 KB, node-pair f16x2 (lo=even)
    __shared__ unsigned int gh2[16 * 128];  // 8 KB, node-pair f16x2 (lo=even)

    const int t    = threadIdx.x;
    const int blk  = blockIdx.x;            // b*256 + slice
    const size_t base = (size_t)blk * 32 * D;
    const int lane = t & 63, wave = t >> 6;
    const int stripe = wave & 1, oh = wave >> 1;
    const int quad = lane >> 4, col = lane & 15;

    // ---- stage x: fp16 GEMM copy + f16x2 node-paired pool copy ----
    const float4* xs4 = (const float4*)(x + base);
#pragma unroll
    for (int it = 0; it < 4; ++it) {
        int idx = t + 256 * it;             // 0..1023
        int r = idx >> 5, c4 = idx & 31;
        float4 v = xs4[idx];
        f16x4 h = { (_Float16)v.x, (_Float16)v.y, (_Float16)v.z, (_Float16)v.w };
        *(f16x4*)&xA[r * 136 + c4 * 4] = h;
    }
#pragma unroll
    for (int it = 0; it < 2; ++it) {
        int idx = t + 256 * it;             // 0..511
        int p = idx >> 5, c4 = idx & 31;
        float4 a = xs4[(2 * p) * 32 + c4];      // even node
        float4 b = xs4[(2 * p + 1) * 32 + c4];  // odd node
        uint4 u;
        u.x = cb((f16x2){(_Float16)a.x, (_Float16)b.x});
        u.y = cb((f16x2){(_Float16)a.y, (_Float16)b.y});
        u.z = cb((f16x2){(_Float16)a.z, (_Float16)b.z});
        u.w = cb((f16x2){(_Float16)a.w, (_Float16)b.w});
        *(uint4*)&xh2[p * 128 + c4 * 4] = u;
    }
    __syncthreads();

    // ---- phase 1: MFMA GEMM + sigmoid -> gh2 ----
    f16x8 af[4];
#pragma unroll
    for (int ks = 0; ks < 4; ++ks)
        af[ks] = *(const f16x8*)&xA[(stripe * 16 + col) * 136 + ks * 32 + quad * 8];

    f32x4 acc[4];
#pragma unroll
    for (int ot = 0; ot < 4; ++ot) acc[ot] = (f32x4){0.f, 0.f, 0.f, 0.f};

#pragma unroll
    for (int ot = 0; ot < 4; ++ot) {
        uint4 bf[4];
#pragma unroll
        for (int ks = 0; ks < 4; ++ks)
            bf[ks] = wfrag[((oh * 4 + ot) * 4 + ks) * 64 + lane];
#pragma unroll
        for (int ks = 0; ks < 4; ++ks)
            acc[ot] = __builtin_amdgcn_mfma_f32_16x16x32_f16(
                af[ks], __builtin_bit_cast(f16x8, bf[ks]), acc[ot], 0, 0, 0);
    }

#pragma unroll
    for (int ot = 0; ot < 4; ++ot) {
        int o = oh * 64 + ot * 16 + col;
        float bv = bias[o];
#pragma unroll
        for (int rr = 0; rr < 2; ++rr) {   // node pair (2rr, 2rr+1) same lane
            float g0 = 1.0f / (1.0f + __expf(-(acc[ot][2 * rr]     + bv)));
            float g1 = 1.0f / (1.0f + __expf(-(acc[ot][2 * rr + 1] + bv)));
            gh2[(stripe * 8 + quad * 2 + rr) * 128 + o] =
                cb((f16x2){(_Float16)g0, (_Float16)g1});
        }
    }
    __syncthreads();

    // ---- phase 2: packed-fp16 max pool, fully unrolled over 16 pairs ----
    const int ti = t >> 4;   // i segs {ti*4..+3} U {64+ti*4..+3}
    const int to = t & 15;   // o segs {to*4..+3} U {64+to*4..+3}
    const f16x2 NEGINF = bc(0xFC00FC00u);

    f16x2 pa[8][8];
#pragma unroll
    for (int ii = 0; ii < 8; ++ii)
#pragma unroll
        for (int oo = 0; oo < 8; ++oo) pa[ii][oo] = NEGINF;

    const unsigned int* xpi = &xh2[ti * 4];
    const unsigned int* gpi = &gh2[to * 4];
#pragma unroll
    for (int p = 0; p < 16; ++p) {
        uint4 xa = *(const uint4*)&xpi[p * 128];
        uint4 xb = *(const uint4*)&xpi[p * 128 + 64];
        uint4 ga = *(const uint4*)&gpi[p * 128];
        uint4 gb = *(const uint4*)&gpi[p * 128 + 64];
        f16x2 xv[8] = {bc(xa.x), bc(xa.y), bc(xa.z), bc(xa.w),
                       bc(xb.x), bc(xb.y), bc(xb.z), bc(xb.w)};
        f16x2 gv[8] = {bc(ga.x), bc(ga.y), bc(ga.z), bc(ga.w),
                       bc(gb.x), bc(gb.y), bc(gb.z), bc(gb.w)};
#pragma unroll
        for (int ii = 0; ii < 8; ++ii)
#pragma unroll
            for (int oo = 0; oo < 8; ++oo)
                pa[ii][oo] = pkmax(pa[ii][oo], xv[ii] * gv[oo]);
    }

    // fold even/odd-node halves and store fp16 slab [i][o]
    uint2* sd = slab + (size_t)blk * 4096;   // 4096 uint2 = 32 KB per slab
#pragma unroll
    for (int ii = 0; ii < 8; ++ii) {
        int ip = (ii < 4) ? (ti * 4 + ii) : (64 + ti * 4 + (ii - 4));
        unsigned int a[8];
#pragma unroll
        for (int oo = 0; oo < 8; ++oo) a[oo] = cb(pa[ii][oo]);
        unsigned int r01 = fold2(a[0]) | (fold2(a[1]) << 16);
        unsigned int r23 = fold2(a[2]) | (fold2(a[3]) << 16);
        unsigned int r45 = fold2(a[4]) | (fold2(a[5]) << 16);
        unsigned int r67 = fold2(a[6]) | (fold2(a[7]) << 16);
        uint2 v0 = {r01, r23};
        uint2 v1 = {r45, r67};
        sd[ip * 32 + to]      = v0;   // o = to*4..+3
        sd[ip * 32 + 16 + to] = v1;   // o = 64+to*4..+3
    }
}

// ---------------------------------------------------------------------------
// Reduce: out[b][o] = (1/128) * sum_i max over 256 slabs (fp16, pk_max).
// grid 512 = (b, i); 256 thr = 64 o-pairs x 4 s-groups; 256 B/wave loads,
// slab stride 8192 uints (32 KB).
// ---------------------------------------------------------------------------
__global__ __launch_bounds__(256) void reduce_kernel(
    const unsigned int* __restrict__ slab, float* __restrict__ out)
{
    __shared__ unsigned int red[3][64];
    const int rb = blockIdx.x;        // 0..511
    const int b  = rb >> 7, i = rb & 127;
    const int t  = threadIdx.x;
    const int og = t & 63, sg = t >> 6;

    const unsigned int* p =
        slab + (size_t)(b * 256 + sg * 64) * 8192 + i * 64 + og;
    f16x2 m = bc(0xFC00FC00u);
#pragma unroll 8
    for (int it = 0; it < 64; ++it)
        m = pkmax(m, bc(p[(size_t)it * 8192]));

    if (sg) red[sg - 1][og] = cb(m);
    __syncthreads();
    if (sg == 0) {
        m = pkmax(m, bc(red[0][og]));
        m = pkmax(m, bc(red[1][og]));
        m = pkmax(m, bc(red[2][og]));
        atomicAdd(&out[b * D + og * 2],     (float)m[0] * 0.0078125f);
        atomicAdd(&out[b * D + og * 2 + 1], (float)m[1] * 0.0078125f);
    }
}

// ---------------------------------------------------------------------------
extern "C" void kernel_launch(void* const* d_in, const int* in_sizes, int n_in,
                              void* d_out, int out_size, void* d_ws, size_t ws_size,
                              hipStream_t stream)
{
    const float* x    = (const float*)d_in[0];   // (4, 8192, 128)
    const float* W    = (const float*)d_in[1];   // (128, 128)
    const float* bias = (const float*)d_in[2];   // (128,)
    float* out = (float*)d_out;                  // (4, 128)

    uint4* wfrag = (uint4*)d_ws;                             // 32 KB
    uint2* slab  = (uint2*)((char*)d_ws + 65536);            // 1024 * 32 KB = 32 MB

    (void)hipMemsetAsync(d_out, 0, (size_t)out_size * sizeof(float), stream);
    wfrag_kernel<<<8, 256, 0, stream>>>(W, wfrag);
    fused_gate_pool<<<1024, 256, 0, stream>>>(x, bias, wfrag, slab);
    reduce_kernel<<<512, 256, 0, stream>>>((const unsigned int*)slab, out);
}

// Round 7
// 101.889 us; speedup vs baseline: 1.4162x; 1.0291x over previous
//
#include <hip/hip_runtime.h>
#include <math.h>

// Problem: B=4, N=8192, Din=Dout=128 fp32.
// out[b][o] = (1/128) * sum_i max_n ( x[b][n][i] * sigmoid(x@W+b)[b][n][o] )
#define D 128
#define NNODES 8192
#define NBATCH 4
#define RW 132          // padded LDS row width (uints) -> bank spread

typedef _Float16 f16x8 __attribute__((ext_vector_type(8)));
typedef _Float16 f16x2 __attribute__((ext_vector_type(2)));
typedef float f32x4 __attribute__((ext_vector_type(4)));

__device__ inline f16x2 bc(unsigned int v) { return __builtin_bit_cast(f16x2, v); }
__device__ inline unsigned int cb(f16x2 v) { return __builtin_bit_cast(unsigned int, v); }
__device__ inline f16x2 pkmax(f16x2 a, f16x2 b) {
    return __builtin_elementwise_max(a, b);   // v_pk_max_f16
}
// max of the two halves of a packed f16x2, result in low 16 bits
__device__ inline unsigned int fold2(unsigned int a) {
    return cb(pkmax(bc(a), bc(a >> 16))) & 0xFFFFu;
}

// ---------------------------------------------------------------------------
// MFMA B-fragments of W^T as fp16; one coalesced dwordx4 per lane:
//   wfrag[(ot*4 + ks)*64 + lane] = W[k][o] halves,
//   o = ot*16 + (lane&15), k = ks*32 + (lane>>4)*8 + j (j=0..7).
// 32 KB, L2/L3-resident. (Layout verified by R5/R6 passing.)
// ---------------------------------------------------------------------------
__global__ __launch_bounds__(256) void wfrag_kernel(
    const float* __restrict__ W, uint4* __restrict__ wfrag)
{
    int e    = blockIdx.x * 256 + threadIdx.x;   // 0..2047
    int lane = e & 63, ks = (e >> 6) & 3, ot = e >> 8;
    int o  = ot * 16 + (lane & 15);
    int kb = ks * 32 + (lane >> 4) * 8;
    f16x8 f;
#pragma unroll
    for (int j = 0; j < 8; ++j) f[j] = (_Float16)W[(kb + j) * D + o];
    wfrag[e] = __builtin_bit_cast(uint4, f);
}

// ---------------------------------------------------------------------------
// Fused gate+pool. grid 512 = B*128 slices of 64 nodes; 256 threads.
// x staged ONCE as node-pair f16x2 (lo = even node), rows padded to 132
// uints. LDS 2*16.9 KB = 33.8 KB -> 2 blocks/CU (grid-limited), 8 waves/CU.
//
// Phase 1 (MFMA): wave w owns node-stripe w (16 nodes), ALL 128 o.
//   A-frags extracted from xh2 via v_perm (lane parity picks lo/hi half).
//   B-frags prefetched one o-tile ahead. 32 MFMA/wave.
//   C/D: col=lane&15, row=quad*4+reg (m89) -> node=w*16+quad*4+reg;
//   epilogue packs node-pairs into gh2 (same layout as xh2).
// Phase 2 (pool): fully unrolled 32 node-pairs, 8i x 8o per thread,
//   v_pk_mul_f16 + v_pk_max_f16. Slab fp16 [i][o] = 32 KB per block.
// ---------------------------------------------------------------------------
__global__ __launch_bounds__(256, 4) void fused_gate_pool(
    const float* __restrict__ x, const float* __restrict__ bias,
    const uint4* __restrict__ wfrag, uint2* __restrict__ slab)
{
    __shared__ unsigned int xh2[32 * RW];   // 16.9 KB node-pair f16x2
    __shared__ unsigned int gh2[32 * RW];   // 16.9 KB gate node-pair f16x2

    const int t    = threadIdx.x;
    const int blk  = blockIdx.x;            // b*128 + slice
    const size_t base = (size_t)blk * 64 * D;
    const int lane = t & 63, wave = t >> 6;
    const int quad = lane >> 4, col = lane & 15;

    // ---- stage x once: pack node-pairs to f16x2 ----
    const float4* xs4 = (const float4*)(x + base);
#pragma unroll
    for (int it = 0; it < 4; ++it) {
        int idx = t + 256 * it;             // 0..1023
        int p = idx >> 5, c4 = idx & 31;    // pair row, feature quad
        float4 a = xs4[(2 * p) * 32 + c4];      // even node
        float4 b = xs4[(2 * p + 1) * 32 + c4];  // odd node
        uint4 u;
        u.x = cb((f16x2){(_Float16)a.x, (_Float16)b.x});
        u.y = cb((f16x2){(_Float16)a.y, (_Float16)b.y});
        u.z = cb((f16x2){(_Float16)a.z, (_Float16)b.z});
        u.w = cb((f16x2){(_Float16)a.w, (_Float16)b.w});
        *(uint4*)&xh2[p * RW + c4 * 4] = u;
    }
    __syncthreads();

    // ---- phase 1: MFMA GEMM + sigmoid -> gh2 ----
    // A-frag: node m = col of stripe -> global node = wave*16+col
    const unsigned int sel = (col & 1) ? 0x07060302u : 0x05040100u;
    const int prow = wave * 8 + (col >> 1);

    f16x8 af[4];
#pragma unroll
    for (int ks = 0; ks < 4; ++ks) {
        int kb = ks * 32 + quad * 8;        // feature base (= uint index)
        uint4 u0 = *(const uint4*)&xh2[prow * RW + kb];
        uint4 u1 = *(const uint4*)&xh2[prow * RW + kb + 4];
        uint4 r;
        r.x = __builtin_amdgcn_perm(u0.y, u0.x, sel);
        r.y = __builtin_amdgcn_perm(u0.w, u0.z, sel);
        r.z = __builtin_amdgcn_perm(u1.y, u1.x, sel);
        r.w = __builtin_amdgcn_perm(u1.w, u1.z, sel);
        af[ks] = __builtin_bit_cast(f16x8, r);
    }

    f32x4 acc[8];
#pragma unroll
    for (int ot = 0; ot < 8; ++ot) acc[ot] = (f32x4){0.f, 0.f, 0.f, 0.f};

    uint4 bf[4];
#pragma unroll
    for (int ks = 0; ks < 4; ++ks) bf[ks] = wfrag[ks * 64 + lane];
#pragma unroll
    for (int ot = 0; ot < 8; ++ot) {
        uint4 cur[4];
#pragma unroll
        for (int ks = 0; ks < 4; ++ks) cur[ks] = bf[ks];
        if (ot < 7) {
#pragma unroll
            for (int ks = 0; ks < 4; ++ks)
                bf[ks] = wfrag[((ot + 1) * 4 + ks) * 64 + lane];
        }
#pragma unroll
        for (int ks = 0; ks < 4; ++ks)
            acc[ot] = __builtin_amdgcn_mfma_f32_16x16x32_f16(
                af[ks], __builtin_bit_cast(f16x8, cur[ks]), acc[ot], 0, 0, 0);
    }

#pragma unroll
    for (int ot = 0; ot < 8; ++ot) {
        int o = ot * 16 + col;
        float bv = bias[o];
#pragma unroll
        for (int rr = 0; rr < 2; ++rr) {    // nodes (2rr, 2rr+1) of this lane
            float g0 = 1.0f / (1.0f + __expf(-(acc[ot][2 * rr]     + bv)));
            float g1 = 1.0f / (1.0f + __expf(-(acc[ot][2 * rr + 1] + bv)));
            gh2[(wave * 8 + quad * 2 + rr) * RW + o] =
                cb((f16x2){(_Float16)g0, (_Float16)g1});
        }
    }
    __syncthreads();

    // ---- phase 2: packed-fp16 max pool, fully unrolled over 32 pairs ----
    const int ti = t >> 4;   // i segs {ti*4..+3} U {64+ti*4..+3}
    const int to = t & 15;   // o segs {to*4..+3} U {64+to*4..+3}

    f16x2 pa[8][8];
#pragma unroll
    for (int ii = 0; ii < 8; ++ii)
#pragma unroll
        for (int oo = 0; oo < 8; ++oo) pa[ii][oo] = bc(0xFC00FC00u);

    const unsigned int* xpi = &xh2[ti * 4];
    const unsigned int* gpi = &gh2[to * 4];
#pragma unroll
    for (int p = 0; p < 32; ++p) {
        uint4 xa = *(const uint4*)&xpi[p * RW];
        uint4 xb = *(const uint4*)&xpi[p * RW + 64];
        uint4 ga = *(const uint4*)&gpi[p * RW];
        uint4 gb = *(const uint4*)&gpi[p * RW + 64];
        f16x2 xv[8] = {bc(xa.x), bc(xa.y), bc(xa.z), bc(xa.w),
                       bc(xb.x), bc(xb.y), bc(xb.z), bc(xb.w)};
        f16x2 gv[8] = {bc(ga.x), bc(ga.y), bc(ga.z), bc(ga.w),
                       bc(gb.x), bc(gb.y), bc(gb.z), bc(gb.w)};
#pragma unroll
        for (int ii = 0; ii < 8; ++ii)
#pragma unroll
            for (int oo = 0; oo < 8; ++oo)
                pa[ii][oo] = pkmax(pa[ii][oo], xv[ii] * gv[oo]);
    }

    // fold even/odd-node halves and store fp16 slab [i][o] (32 KB/block)
    uint2* sd = slab + (size_t)blk * 4096;
#pragma unroll
    for (int ii = 0; ii < 8; ++ii) {
        int ip = (ii < 4) ? (ti * 4 + ii) : (64 + ti * 4 + (ii - 4));
        unsigned int a[8];
#pragma unroll
        for (int oo = 0; oo < 8; ++oo) a[oo] = cb(pa[ii][oo]);
        unsigned int r01 = fold2(a[0]) | (fold2(a[1]) << 16);
        unsigned int r23 = fold2(a[2]) | (fold2(a[3]) << 16);
        unsigned int r45 = fold2(a[4]) | (fold2(a[5]) << 16);
        unsigned int r67 = fold2(a[6]) | (fold2(a[7]) << 16);
        uint2 v0 = {r01, r23};
        uint2 v1 = {r45, r67};
        sd[ip * 32 + to]      = v0;   // o = to*4..+3
        sd[ip * 32 + 16 + to] = v1;   // o = 64+to*4..+3
    }
}

// ---------------------------------------------------------------------------
// Reduce: out[b][o] = (1/128) * sum_i max over 128 slabs (fp16, pk_max).
// grid 512 = (b, i); 256 thr = 64 o-pairs x 4 s-groups; 256 B/wave rows,
// slab stride 8192 uints (32 KB).
// ---------------------------------------------------------------------------
__global__ __launch_bounds__(256) void reduce_kernel(
    const unsigned int* __restrict__ slab, float* __restrict__ out)
{
    __shared__ unsigned int red[3][64];
    const int rb = blockIdx.x;        // 0..511
    const int b  = rb >> 7, i = rb & 127;
    const int t  = threadIdx.x;
    const int og = t & 63, sg = t >> 6;

    const unsigned int* p =
        slab + (size_t)(b * 128 + sg * 32) * 8192 + i * 64 + og;
    f16x2 m = bc(0xFC00FC00u);
#pragma unroll 8
    for (int it = 0; it < 32; ++it)
        m = pkmax(m, bc(p[(size_t)it * 8192]));

    if (sg) red[sg - 1][og] = cb(m);
    __syncthreads();
    if (sg == 0) {
        m = pkmax(m, bc(red[0][og]));
        m = pkmax(m, bc(red[1][og]));
        m = pkmax(m, bc(red[2][og]));
        atomicAdd(&out[b * D + og * 2],     (float)m[0] * 0.0078125f);
        atomicAdd(&out[b * D + og * 2 + 1], (float)m[1] * 0.0078125f);
    }
}

// ---------------------------------------------------------------------------
extern "C" void kernel_launch(void* const* d_in, const int* in_sizes, int n_in,
                              void* d_out, int out_size, void* d_ws, size_t ws_size,
                              hipStream_t stream)
{
    const float* x    = (const float*)d_in[0];   // (4, 8192, 128)
    const float* W    = (const float*)d_in[1];   // (128, 128)
    const float* bias = (const float*)d_in[2];   // (128,)
    float* out = (float*)d_out;                  // (4, 128)

    uint4* wfrag = (uint4*)d_ws;                             // 32 KB
    uint2* slab  = (uint2*)((char*)d_ws + 65536);            // 512 * 32 KB = 16 MB

    (void)hipMemsetAsync(d_out, 0, (size_t)out_size * sizeof(float), stream);
    wfrag_kernel<<<8, 256, 0, stream>>>(W, wfrag);
    fused_gate_pool<<<512, 256, 0, stream>>>(x, bias, wfrag, slab);
    reduce_kernel<<<512, 256, 0, stream>>>((const unsigned int*)slab, out);
}

// Round 8
// 101.750 us; speedup vs baseline: 1.4181x; 1.0014x over previous
//
#include <hip/hip_runtime.h>
#include <math.h>

// Problem: B=4, N=8192, Din=Dout=128 fp32.
// out[b][o] = (1/128) * sum_i max_n ( x[b][n][i] * sigmoid(x@W+b)[b][n][o] )
#define D 128
#define NNODES 8192
#define NBATCH 4
#define RW 132          // padded LDS row width (uints) -> bank spread

typedef _Float16 f16x8 __attribute__((ext_vector_type(8)));
typedef _Float16 f16x2 __attribute__((ext_vector_type(2)));
typedef float f32x4 __attribute__((ext_vector_type(4)));

__device__ inline f16x2 bc(unsigned int v) { return __builtin_bit_cast(f16x2, v); }
__device__ inline unsigned int cb(f16x2 v) { return __builtin_bit_cast(unsigned int, v); }
__device__ inline f16x2 pkmax(f16x2 a, f16x2 b) {
    return __builtin_elementwise_max(a, b);   // v_pk_max_f16
}
// max of the two halves of a packed f16x2, result in low 16 bits
__device__ inline unsigned int fold2(unsigned int a) {
    return cb(pkmax(bc(a), bc(a >> 16))) & 0xFFFFu;
}

// ---------------------------------------------------------------------------
// MFMA B-fragments of W^T as fp16; one coalesced dwordx4 per lane:
//   wfrag[(ot*4 + ks)*64 + lane] = W[k][o] halves,
//   o = ot*16 + (lane&15), k = ks*32 + (lane>>4)*8 + j (j=0..7).
// 32 KB, L2/L3-resident. Also zeroes d_out (4*128 floats) -> saves the
// separate hipMemsetAsync dispatch in the graph.
// ---------------------------------------------------------------------------
__global__ __launch_bounds__(256) void wfrag_kernel(
    const float* __restrict__ W, uint4* __restrict__ wfrag,
    float* __restrict__ out)
{
    int e    = blockIdx.x * 256 + threadIdx.x;   // 0..2047
    if (e < NBATCH * D) out[e] = 0.0f;           // zero d_out (512 floats)
    int lane = e & 63, ks = (e >> 6) & 3, ot = e >> 8;
    int o  = ot * 16 + (lane & 15);
    int kb = ks * 32 + (lane >> 4) * 8;
    f16x8 f;
#pragma unroll
    for (int j = 0; j < 8; ++j) f[j] = (_Float16)W[(kb + j) * D + o];
    wfrag[e] = __builtin_bit_cast(uint4, f);
}

// ---------------------------------------------------------------------------
// Fused gate+pool. grid 512 = B*128 slices of 64 nodes; 256 threads.
// x staged ONCE as node-pair f16x2 (lo = even node), rows padded to 132
// uints. LDS 2*16.9 KB = 33.8 KB; grid gives 2 blocks/CU.
// launch_bounds(256,2): VGPR budget 256 — phase 2 holds 64 acc regs + the
// unrolled load schedule; the old (256,4)=128-VGPR cap likely forced
// scratch spills (R6/R7 underperformed the VALU model by ~2x).
//
// Phase 1 (MFMA): wave w owns node-stripe w (16 nodes), ALL 128 o.
//   A-frags extracted from xh2 via v_perm (lane parity picks lo/hi half).
//   B-frags prefetched one o-tile ahead. 32 MFMA/wave.
//   C/D: col=lane&15, row=quad*4+reg (m89) -> node=w*16+quad*4+reg;
//   epilogue packs node-pairs into gh2 (same layout as xh2).
// Phase 2 (pool): fully unrolled 32 node-pairs, 8i x 8o per thread,
//   v_pk_mul_f16 + v_pk_max_f16. Slab fp16 [i][o] = 32 KB per block.
// ---------------------------------------------------------------------------
__global__ __launch_bounds__(256, 2) void fused_gate_pool(
    const float* __restrict__ x, const float* __restrict__ bias,
    const uint4* __restrict__ wfrag, uint2* __restrict__ slab)
{
    __shared__ unsigned int xh2[32 * RW];   // 16.9 KB node-pair f16x2
    __shared__ unsigned int gh2[32 * RW];   // 16.9 KB gate node-pair f16x2

    const int t    = threadIdx.x;
    const int blk  = blockIdx.x;            // b*128 + slice
    const size_t base = (size_t)blk * 64 * D;
    const int lane = t & 63, wave = t >> 6;
    const int quad = lane >> 4, col = lane & 15;

    // ---- stage x once: pack node-pairs to f16x2 ----
    const float4* xs4 = (const float4*)(x + base);
#pragma unroll
    for (int it = 0; it < 4; ++it) {
        int idx = t + 256 * it;             // 0..1023
        int p = idx >> 5, c4 = idx & 31;    // pair row, feature quad
        float4 a = xs4[(2 * p) * 32 + c4];      // even node
        float4 b = xs4[(2 * p + 1) * 32 + c4];  // odd node
        uint4 u;
        u.x = cb((f16x2){(_Float16)a.x, (_Float16)b.x});
        u.y = cb((f16x2){(_Float16)a.y, (_Float16)b.y});
        u.z = cb((f16x2){(_Float16)a.z, (_Float16)b.z});
        u.w = cb((f16x2){(_Float16)a.w, (_Float16)b.w});
        *(uint4*)&xh2[p * RW + c4 * 4] = u;
    }
    __syncthreads();

    // ---- phase 1: MFMA GEMM + sigmoid -> gh2 ----
    const unsigned int sel = (col & 1) ? 0x07060302u : 0x05040100u;
    const int prow = wave * 8 + (col >> 1);

    f16x8 af[4];
#pragma unroll
    for (int ks = 0; ks < 4; ++ks) {
        int kb = ks * 32 + quad * 8;        // feature base (= uint index)
        uint4 u0 = *(const uint4*)&xh2[prow * RW + kb];
        uint4 u1 = *(const uint4*)&xh2[prow * RW + kb + 4];
        uint4 r;
        r.x = __builtin_amdgcn_perm(u0.y, u0.x, sel);
        r.y = __builtin_amdgcn_perm(u0.w, u0.z, sel);
        r.z = __builtin_amdgcn_perm(u1.y, u1.x, sel);
        r.w = __builtin_amdgcn_perm(u1.w, u1.z, sel);
        af[ks] = __builtin_bit_cast(f16x8, r);
    }

    f32x4 acc[8];
#pragma unroll
    for (int ot = 0; ot < 8; ++ot) acc[ot] = (f32x4){0.f, 0.f, 0.f, 0.f};

    uint4 bf[4];
#pragma unroll
    for (int ks = 0; ks < 4; ++ks) bf[ks] = wfrag[ks * 64 + lane];
#pragma unroll
    for (int ot = 0; ot < 8; ++ot) {
        uint4 cur[4];
#pragma unroll
        for (int ks = 0; ks < 4; ++ks) cur[ks] = bf[ks];
        if (ot < 7) {
#pragma unroll
            for (int ks = 0; ks < 4; ++ks)
                bf[ks] = wfrag[((ot + 1) * 4 + ks) * 64 + lane];
        }
#pragma unroll
        for (int ks = 0; ks < 4; ++ks)
            acc[ot] = __builtin_amdgcn_mfma_f32_16x16x32_f16(
                af[ks], __builtin_bit_cast(f16x8, cur[ks]), acc[ot], 0, 0, 0);
    }

#pragma unroll
    for (int ot = 0; ot < 8; ++ot) {
        int o = ot * 16 + col;
        float bv = bias[o];
#pragma unroll
        for (int rr = 0; rr < 2; ++rr) {    // nodes (2rr, 2rr+1) of this lane
            float g0 = 1.0f / (1.0f + __expf(-(acc[ot][2 * rr]     + bv)));
            float g1 = 1.0f / (1.0f + __expf(-(acc[ot][2 * rr + 1] + bv)));
            gh2[(wave * 8 + quad * 2 + rr) * RW + o] =
                cb((f16x2){(_Float16)g0, (_Float16)g1});
        }
    }
    __syncthreads();

    // ---- phase 2: packed-fp16 max pool, fully unrolled over 32 pairs ----
    const int ti = t >> 4;   // i segs {ti*4..+3} U {64+ti*4..+3}
    const int to = t & 15;   // o segs {to*4..+3} U {64+to*4..+3}

    f16x2 pa[8][8];
#pragma unroll
    for (int ii = 0; ii < 8; ++ii)
#pragma unroll
        for (int oo = 0; oo < 8; ++oo) pa[ii][oo] = bc(0xFC00FC00u);

    const unsigned int* xpi = &xh2[ti * 4];
    const unsigned int* gpi = &gh2[to * 4];
#pragma unroll
    for (int p = 0; p < 32; ++p) {
        uint4 xa = *(const uint4*)&xpi[p * RW];
        uint4 xb = *(const uint4*)&xpi[p * RW + 64];
        uint4 ga = *(const uint4*)&gpi[p * RW];
        uint4 gb = *(const uint4*)&gpi[p * RW + 64];
        f16x2 xv[8] = {bc(xa.x), bc(xa.y), bc(xa.z), bc(xa.w),
                       bc(xb.x), bc(xb.y), bc(xb.z), bc(xb.w)};
        f16x2 gv[8] = {bc(ga.x), bc(ga.y), bc(ga.z), bc(ga.w),
                       bc(gb.x), bc(gb.y), bc(gb.z), bc(gb.w)};
#pragma unroll
        for (int ii = 0; ii < 8; ++ii)
#pragma unroll
            for (int oo = 0; oo < 8; ++oo)
                pa[ii][oo] = pkmax(pa[ii][oo], xv[ii] * gv[oo]);
    }

    // fold even/odd-node halves and store fp16 slab [i][o] (32 KB/block)
    uint2* sd = slab + (size_t)blk * 4096;
#pragma unroll
    for (int ii = 0; ii < 8; ++ii) {
        int ip = (ii < 4) ? (ti * 4 + ii) : (64 + ti * 4 + (ii - 4));
        unsigned int a[8];
#pragma unroll
        for (int oo = 0; oo < 8; ++oo) a[oo] = cb(pa[ii][oo]);
        unsigned int r01 = fold2(a[0]) | (fold2(a[1]) << 16);
        unsigned int r23 = fold2(a[2]) | (fold2(a[3]) << 16);
        unsigned int r45 = fold2(a[4]) | (fold2(a[5]) << 16);
        unsigned int r67 = fold2(a[6]) | (fold2(a[7]) << 16);
        uint2 v0 = {r01, r23};
        uint2 v1 = {r45, r67};
        sd[ip * 32 + to]      = v0;   // o = to*4..+3
        sd[ip * 32 + 16 + to] = v1;   // o = 64+to*4..+3
    }
}

// ---------------------------------------------------------------------------
// Reduce: out[b][o] = (1/128) * sum_i max over 128 slabs (fp16, pk_max).
// grid 512 = (b, i); 256 thr = 64 o-pairs x 4 s-groups; 256 B/wave rows,
// slab stride 8192 uints (32 KB).
// ---------------------------------------------------------------------------
__global__ __launch_bounds__(256) void reduce_kernel(
    const unsigned int* __restrict__ slab, float* __restrict__ out)
{
    __shared__ unsigned int red[3][64];
    const int rb = blockIdx.x;        // 0..511
    const int b  = rb >> 7, i = rb & 127;
    const int t  = threadIdx.x;
    const int og = t & 63, sg = t >> 6;

    const unsigned int* p =
        slab + (size_t)(b * 128 + sg * 32) * 8192 + i * 64 + og;
    f16x2 m = bc(0xFC00FC00u);
#pragma unroll 8
    for (int it = 0; it < 32; ++it)
        m = pkmax(m, bc(p[(size_t)it * 8192]));

    if (sg) red[sg - 1][og] = cb(m);
    __syncthreads();
    if (sg == 0) {
        m = pkmax(m, bc(red[0][og]));
        m = pkmax(m, bc(red[1][og]));
        m = pkmax(m, bc(red[2][og]));
        atomicAdd(&out[b * D + og * 2],     (float)m[0] * 0.0078125f);
        atomicAdd(&out[b * D + og * 2 + 1], (float)m[1] * 0.0078125f);
    }
}

// ---------------------------------------------------------------------------
extern "C" void kernel_launch(void* const* d_in, const int* in_sizes, int n_in,
                              void* d_out, int out_size, void* d_ws, size_t ws_size,
                              hipStream_t stream)
{
    const float* x    = (const float*)d_in[0];   // (4, 8192, 128)
    const float* W    = (const float*)d_in[1];   // (128, 128)
    const float* bias = (const float*)d_in[2];   // (128,)
    float* out = (float*)d_out;                  // (4, 128)

    uint4* wfrag = (uint4*)d_ws;                             // 32 KB
    uint2* slab  = (uint2*)((char*)d_ws + 65536);            // 512 * 32 KB = 16 MB

    wfrag_kernel<<<8, 256, 0, stream>>>(W, wfrag, out);      // also zeroes out
    fused_gate_pool<<<512, 256, 0, stream>>>(x, bias, wfrag, slab);
    reduce_kernel<<<512, 256, 0, stream>>>((const unsigned int*)slab, out);
}